// Round 1
// baseline (198.051 us; speedup 1.0000x reference)
//
#include <hip/hip_runtime.h>
#include <stdint.h>

#define BI 128
#define BT 128
#define RR 36
#define WW 50
#define DD 1024
#define RP 48
#define WP 64
#define SEPS 1e-6f

typedef __attribute__((ext_vector_type(8))) short short8v;
typedef __attribute__((ext_vector_type(4))) float float4v;

__device__ __forceinline__ unsigned short f2bf(float f){
  unsigned u = __float_as_uint(f);
  return (unsigned short)((u + 0x7FFFu + ((u >> 16) & 1u)) >> 16);
}

// Convert + zero-pad both tensors to bf16 in workspace.
// Block b < BI*RP: A row (i, r); else B row (c, w). 256 thr x 4 elems = 1024.
__global__ __launch_bounds__(256) void cvt_kernel(
    const float* __restrict__ imgs, const float* __restrict__ caps,
    unsigned short* __restrict__ Ab, unsigned short* __restrict__ Bb){
  int b = blockIdx.x;
  int t = threadIdx.x;
  if (b < BI * RP){
    int r = b % RP;
    ushort4 o = make_ushort4(0, 0, 0, 0);
    if (r < RR){
      int i = b / RP;
      const float4 v = *(const float4*)(imgs + ((size_t)(i * RR + r)) * DD + t * 4);
      o.x = f2bf(v.x); o.y = f2bf(v.y); o.z = f2bf(v.z); o.w = f2bf(v.w);
    }
    *(ushort4*)(Ab + ((size_t)b) * DD + t * 4) = o;
  } else {
    int bb = b - BI * RP;
    int w = bb % WP;
    ushort4 o = make_ushort4(0, 0, 0, 0);
    if (w < WW){
      int c = bb / WP;
      const float4 v = *(const float4*)(caps + ((size_t)(c * WW + w)) * DD + t * 4);
      o.x = f2bf(v.x); o.y = f2bf(v.y); o.z = f2bf(v.z); o.w = f2bf(v.w);
    }
    *(ushort4*)(Bb + ((size_t)bb) * DD + t * 4) = o;
  }
}

// ---- wave-wide reductions: DPP rotation-reduce within 16, shfl_xor across ----
template<int CTRL>
__device__ __forceinline__ float dpp_add(float x){
  int y = __builtin_amdgcn_mov_dpp(__float_as_int(x), CTRL, 0xF, 0xF, true);
  return x + __int_as_float(y);
}
__device__ __forceinline__ float waveAllSum(float x){
  x = dpp_add<0x121>(x);   // row_ror:1
  x = dpp_add<0x122>(x);   // row_ror:2
  x = dpp_add<0x124>(x);   // row_ror:4
  x = dpp_add<0x128>(x);   // row_ror:8  -> every lane has its 16-group sum
  x += __shfl_xor(x, 16);
  x += __shfl_xor(x, 32);
  return x;
}

// LDS: stage region 1792 units x 16B = 28672 B (A: units 0..767 [2 imgs x 48 rows x 8],
// B: units 768..1791 [2 caps x 64 rows x 8]).  Sinkhorn fg scratch (4 waves x 36 x 51 f32
// = 29376 B) is a union over the same space, used after the final barrier.
#define LDSB 29440

__global__ __launch_bounds__(256) void wass_kernel(
    const unsigned short* __restrict__ Ab, const unsigned short* __restrict__ Bb,
    const int* __restrict__ il, const int* __restrict__ cl,
    float* __restrict__ out){
  __shared__ __align__(16) unsigned char LDS[LDSB];
  const int tid  = threadIdx.x;
  const int lane = tid & 63;
  const int wv   = tid >> 6;
  const int bx   = blockIdx.x;
  const int i0 = (bx >> 6) * 2;     // 64 i-blocks x 64 c-blocks
  const int c0 = (bx & 63) * 2;
  const int ia = wv >> 1, cc = wv & 1;   // this wave's pair
  const int ii = i0 + ia, ci = c0 + cc;
  const int l15 = lane & 15;
  const int lhi = lane >> 4;

  // Precompute the 7 per-thread staging sources (16B units). XOR-swizzle is applied
  // on the GLOBAL source (k-group kg_log = kg_phys ^ (row&7)); LDS dest stays linear
  // (global_load_lds requirement), fragment reads apply the same XOR.
  const unsigned short* srcp[7];
  #pragma unroll
  for (int j = 0; j < 7; j++){
    int u = j * 256 + tid;
    if (u < 768){                       // A region
      int a  = (u >= 384) ? 1 : 0;
      int us = u - a * 384;
      int row = us >> 3;
      int kg  = (us & 7) ^ (row & 7);
      srcp[j] = Ab + ((size_t)((i0 + a) * RP + row)) * DD + kg * 8;
    } else {                            // B region
      int ub = u - 768;
      int bcap = ub >> 9;
      int us = ub & 511;
      int row = us >> 3;
      int kg  = (us & 7) ^ (row & 7);
      srcp[j] = Bb + ((size_t)((c0 + bcap) * WP + row)) * DD + kg * 8;
    }
  }

  float4v acc[3][4];
  #pragma unroll
  for (int a1 = 0; a1 < 3; a1++)
    #pragma unroll
    for (int b1 = 0; b1 < 4; b1++)
      acc[a1][b1] = (float4v){0.f, 0.f, 0.f, 0.f};

  for (int ch = 0; ch < 16; ch++){      // K chunks of 64
    __syncthreads();                    // prev chunk's readers done
    #pragma unroll
    for (int j = 0; j < 7; j++){
      __builtin_amdgcn_global_load_lds(
          (const __attribute__((address_space(1))) void*)(srcp[j] + ch * 64),
          (__attribute__((address_space(3))) void*)(LDS + (j * 256 + wv * 64) * 16),
          16, 0, 0);
    }
    __syncthreads();                    // drains vmcnt -> staged data visible
    #pragma unroll
    for (int s = 0; s < 2; s++){        // two K=32 steps per chunk
      short8v af[3], bf[4];
      int kb = s * 4 + lhi;             // logical k-group 0..7
      #pragma unroll
      for (int tr = 0; tr < 3; tr++){
        int row = tr * 16 + l15;
        af[tr] = *(const short8v*)(LDS + (ia * 384 + row * 8 + (kb ^ (row & 7))) * 16);
      }
      #pragma unroll
      for (int tw = 0; tw < 4; tw++){
        int row = tw * 16 + l15;
        bf[tw] = *(const short8v*)(LDS + (768 + cc * 512 + row * 8 + (kb ^ (row & 7))) * 16);
      }
      #pragma unroll
      for (int tr = 0; tr < 3; tr++)
        #pragma unroll
        for (int tw = 0; tw < 4; tw++)
          acc[tr][tw] = __builtin_amdgcn_mfma_f32_16x16x32_bf16(
              af[tr], bf[tw], acc[tr][tw], 0, 0, 0);
    }
  }
  __syncthreads();   // everyone done reading stage LDS before fg-scratch overwrites it

  // ---- transpose C-frags (col=lane&15, row=(lane>>4)*4+reg; m89/m91) into LDS ----
  float* fgS = (float*)(void*)LDS + (size_t)wv * (RR * 51);
  #pragma unroll
  for (int tr = 0; tr < 3; tr++){
    #pragma unroll
    for (int j = 0; j < 4; j++){
      int r = tr * 16 + lhi * 4 + j;
      if (r < RR){
        #pragma unroll
        for (int tw = 0; tw < 4; tw++){
          int w2 = tw * 16 + l15;
          if (w2 < WW) fgS[r * 51 + w2] = acc[tr][tw][j];
        }
      }
    }
  }
  __builtin_amdgcn_s_waitcnt(0);  // DS writes complete (wave-local scratch, no barrier)

  // ---- per-wave Sinkhorn, P column-per-lane (lane = word index w) ----
  const int ilen = il[ii];
  const int clen = cl[ci];
  const float inv_il = __fdividef(1.0f, (float)ilen);
  const float inv_cl = __fdividef(1.0f, (float)clen);
  const int w = lane;
  const bool vw = (w < clen);

  float p[RR];
  #pragma unroll
  for (int r = 0; r < RR; r++){
    float f = (w < WW) ? fgS[r * 51 + w] : 0.0f;
    p[r] = (vw && (r < ilen)) ? __expf(f * 20.0f - 20.0f) : 0.0f;  // exp(-(1-fg)/0.05)
  }
  float s0 = 0.f;
  #pragma unroll
  for (int r = 0; r < RR; r++) s0 += p[r];
  s0 = waveAllSum(s0);
  float sc = __fdividef(1.0f, s0 + SEPS);     // P /= (sum + EPS)
  #pragma unroll
  for (int r = 0; r < RR; r++) p[r] *= sc;

  for (int it = 0; it < 3; it++){
    #pragma unroll
    for (int r = 0; r < RR; r++){             // u = rowsum + EPS ; P *= r/u
      float t = waveAllSum(p[r]);
      p[r] *= __fdividef(inv_il, t + SEPS);
    }
    float v = 0.f;                            // v = colsum + EPS (in-lane) ; P *= c/v
    #pragma unroll
    for (int r = 0; r < RR; r++) v += p[r];
    float cs = __fdividef(inv_cl, v + SEPS);
    #pragma unroll
    for (int r = 0; r < RR; r++) p[r] *= cs;
  }

  float sim = 0.f;
  #pragma unroll
  for (int r = 0; r < RR; r++){
    float f = (w < WW) ? fgS[r * 51 + w] : 0.0f;   // re-read fg (saves 36 VGPRs)
    sim = fmaf(f, p[r], sim);
  }
  sim = waveAllSum(sim);
  if (lane == 0) out[ii * BT + ci] = sim;
}

extern "C" void kernel_launch(void* const* d_in, const int* in_sizes, int n_in,
                              void* d_out, int out_size, void* d_ws, size_t ws_size,
                              hipStream_t stream){
  const float* imgs = (const float*)d_in[0];
  const float* caps = (const float*)d_in[1];
  const int* il = (const int*)d_in[2];
  const int* cl = (const int*)d_in[3];
  float* out = (float*)d_out;
  unsigned short* Ab = (unsigned short*)d_ws;                 // [128][48][1024] bf16
  unsigned short* Bb = Ab + (size_t)BI * RP * DD;             // [128][64][1024] bf16

  cvt_kernel<<<BI * RP + BT * WP, 256, 0, stream>>>(imgs, caps, Ab, Bb);
  wass_kernel<<<(BI / 2) * (BT / 2), 256, 0, stream>>>(Ab, Bb, il, cl, out);
}

// Round 2
// 185.415 us; speedup vs baseline: 1.0682x; 1.0682x over previous
//
#include <hip/hip_runtime.h>
#include <stdint.h>

#define BI 128
#define BT 128
#define RR 36
#define WW 50
#define DD 1024
#define MM (BI*RR)   /* 4608 */
#define NN (BT*WW)   /* 6400 */
#define SEPS 1e-6f

typedef __attribute__((ext_vector_type(8))) short short8v;
typedef __attribute__((ext_vector_type(4))) float float4v;

__device__ __forceinline__ unsigned short f2bf(float f){
  unsigned u = __float_as_uint(f);
  return (unsigned short)((u + 0x7FFFu + ((u >> 16) & 1u)) >> 16);
}

// ---- flat f32 -> bf16 convert (no padding needed: M,N divisible by 128) ----
__global__ __launch_bounds__(256) void cvt_kernel(
    const float* __restrict__ src, unsigned short* __restrict__ dst, int n8){
  int g = blockIdx.x * 256 + threadIdx.x;
  if (g >= n8) return;
  const float4 a = ((const float4*)src)[g * 2 + 0];
  const float4 b = ((const float4*)src)[g * 2 + 1];
  ushort4 lo = make_ushort4(f2bf(a.x), f2bf(a.y), f2bf(a.z), f2bf(a.w));
  ushort4 hi = make_ushort4(f2bf(b.x), f2bf(b.y), f2bf(b.z), f2bf(b.w));
  ((ushort4*)dst)[g * 2 + 0] = lo;
  ((ushort4*)dst)[g * 2 + 1] = hi;
}

// ---- m97-structure 128x128x64 GEMM: C[M][N] f32 = A[M][K] * B[N][K]^T, bf16 ----
// LDS 32KB (A-tile 128x64 + B-tile 128x64, linear dest for global_load_lds,
// XOR-swizzle applied on the global SOURCE address; frag reads re-apply it).
__global__ __launch_bounds__(256) void gemm_kernel(
    const unsigned short* __restrict__ A, const unsigned short* __restrict__ B,
    float* __restrict__ C){
  __shared__ __align__(16) unsigned char LDS[32768];
  const int tid = threadIdx.x;
  const int lane = tid & 63, wv = tid >> 6;
  const int l15 = lane & 15, lhi = lane >> 4;
  const int bx = blockIdx.x;
  const int swz = (bx & 7) * 225 + (bx >> 3);     // 1800 = 8*225, bijective
  const int mb = swz / 50, nb = swz % 50;         // 36 x 50 tile grid
  const int m0 = mb * 128, n0 = nb * 128;
  const int wr = wv >> 1, wc = wv & 1;            // 2x2 wave grid, 64x64 per wave

  const unsigned short* sA[4];
  const unsigned short* sB[4];
  #pragma unroll
  for (int j = 0; j < 4; j++){
    int u = j * 256 + tid;                        // 16B unit 0..1023
    int row = u >> 3;
    int kg = (u & 7) ^ (row & 7);                 // source pre-swizzle
    sA[j] = A + (size_t)(m0 + row) * DD + kg * 8;
    sB[j] = B + (size_t)(n0 + row) * DD + kg * 8;
  }

  float4v acc[4][4];
  #pragma unroll
  for (int a1 = 0; a1 < 4; a1++)
    #pragma unroll
    for (int b1 = 0; b1 < 4; b1++)
      acc[a1][b1] = (float4v){0.f, 0.f, 0.f, 0.f};

  for (int ch = 0; ch < 16; ch++){
    __syncthreads();
    #pragma unroll
    for (int j = 0; j < 4; j++){
      __builtin_amdgcn_global_load_lds(
          (const __attribute__((address_space(1))) void*)(sA[j] + ch * 64),
          (__attribute__((address_space(3))) void*)(LDS + (j * 256 + tid) * 16),
          16, 0, 0);
      __builtin_amdgcn_global_load_lds(
          (const __attribute__((address_space(1))) void*)(sB[j] + ch * 64),
          (__attribute__((address_space(3))) void*)(LDS + 16384 + (j * 256 + tid) * 16),
          16, 0, 0);
    }
    __syncthreads();
    #pragma unroll
    for (int s = 0; s < 2; s++){
      int kb = s * 4 + lhi;                       // logical k-group 0..7
      short8v af[4], bf[4];
      #pragma unroll
      for (int tr = 0; tr < 4; tr++){
        int row = wr * 64 + tr * 16 + l15;
        af[tr] = *(const short8v*)(LDS + (row * 8 + (kb ^ (row & 7))) * 16);
      }
      #pragma unroll
      for (int tw = 0; tw < 4; tw++){
        int row = wc * 64 + tw * 16 + l15;
        bf[tw] = *(const short8v*)(LDS + 16384 + (row * 8 + (kb ^ (row & 7))) * 16);
      }
      #pragma unroll
      for (int tr = 0; tr < 4; tr++)
        #pragma unroll
        for (int tw = 0; tw < 4; tw++)
          acc[tr][tw] = __builtin_amdgcn_mfma_f32_16x16x32_bf16(
              af[tr], bf[tw], acc[tr][tw], 0, 0, 0);
    }
  }

  // C/D layout (m89/m91, validated in round 1): col = lane&15, row = lhi*4 + j
  #pragma unroll
  for (int tr = 0; tr < 4; tr++)
    #pragma unroll
    for (int tw = 0; tw < 4; tw++)
      #pragma unroll
      for (int j = 0; j < 4; j++){
        int m = m0 + wr * 64 + tr * 16 + lhi * 4 + j;
        int n = n0 + wc * 64 + tw * 16 + l15;
        C[(size_t)m * NN + n] = acc[tr][tw][j];
      }
}

// ---- wave-wide sum: DPP row_ror within 16, shfl_xor across 16/32 ----
template<int CTRL>
__device__ __forceinline__ float dpp_add(float x){
  int y = __builtin_amdgcn_mov_dpp(__float_as_int(x), CTRL, 0xF, 0xF, true);
  return x + __int_as_float(y);
}
__device__ __forceinline__ float waveAllSum(float x){
  x = dpp_add<0x121>(x);
  x = dpp_add<0x122>(x);
  x = dpp_add<0x124>(x);
  x = dpp_add<0x128>(x);
  x += __shfl_xor(x, 16);
  x += __shfl_xor(x, 32);
  return x;
}

// ---- per-wave Sinkhorn over fg[i][c] 36x50 tiles; lane = word index w ----
__global__ __launch_bounds__(256) void sink_kernel(
    const float* __restrict__ fg, const int* __restrict__ il,
    const int* __restrict__ cl, float* __restrict__ out){
  const int lane = threadIdx.x & 63;
  const int gw = blockIdx.x * 4 + (threadIdx.x >> 6);
  const int i = gw >> 7, c = gw & 127;
  const float* base = fg + (size_t)(i * RR) * NN + c * WW;
  const int w = lane;

  const int ilen = il[i];
  const int clen = cl[c];
  const float inv_il = __fdividef(1.0f, (float)ilen);
  const float inv_cl = __fdividef(1.0f, (float)clen);
  const bool vw = (w < clen);

  float f[RR], p[RR];
  #pragma unroll
  for (int r = 0; r < RR; r++)
    f[r] = (w < WW) ? base[(size_t)r * NN + w] : 0.0f;
  #pragma unroll
  for (int r = 0; r < RR; r++)
    p[r] = (vw && (r < ilen)) ? __expf(f[r] * 20.0f - 20.0f) : 0.0f;

  float s0 = 0.f;
  #pragma unroll
  for (int r = 0; r < RR; r++) s0 += p[r];
  s0 = waveAllSum(s0);
  float sc = __fdividef(1.0f, s0 + SEPS);
  #pragma unroll
  for (int r = 0; r < RR; r++) p[r] *= sc;

  for (int it = 0; it < 3; it++){
    #pragma unroll
    for (int r = 0; r < RR; r++){
      float t = waveAllSum(p[r]);                 // u = rowsum + EPS
      p[r] *= __fdividef(inv_il, t + SEPS);
    }
    float v = 0.f;                                // colsum (in-lane)
    #pragma unroll
    for (int r = 0; r < RR; r++) v += p[r];
    float cs = __fdividef(inv_cl, v + SEPS);
    #pragma unroll
    for (int r = 0; r < RR; r++) p[r] *= cs;
  }

  float sim = 0.f;
  #pragma unroll
  for (int r = 0; r < RR; r++) sim = fmaf(f[r], p[r], sim);
  sim = waveAllSum(sim);
  if (lane == 0) out[i * BT + c] = sim;
}

extern "C" void kernel_launch(void* const* d_in, const int* in_sizes, int n_in,
                              void* d_out, int out_size, void* d_ws, size_t ws_size,
                              hipStream_t stream){
  const float* imgs = (const float*)d_in[0];
  const float* caps = (const float*)d_in[1];
  const int* il = (const int*)d_in[2];
  const int* cl = (const int*)d_in[3];
  float* out = (float*)d_out;

  unsigned short* Ab = (unsigned short*)d_ws;               // [4608][1024] bf16
  unsigned short* Bb = Ab + (size_t)MM * DD;                // [6400][1024] bf16
  float* fg = (float*)(Bb + (size_t)NN * DD);               // [4608][6400] f32

  const int n8A = MM * DD / 8;                              // 589824
  const int n8B = NN * DD / 8;                              // 819200
  cvt_kernel<<<(n8A + 255) / 256, 256, 0, stream>>>(imgs, Ab, n8A);
  cvt_kernel<<<(n8B + 255) / 256, 256, 0, stream>>>(caps, Bb, n8B);
  gemm_kernel<<<36 * 50, 256, 0, stream>>>(Ab, Bb, fg);
  sink_kernel<<<(BI * BT) / 4, 256, 0, stream>>>(fg, il, cl, out);
}

// Round 3
// 153.006 us; speedup vs baseline: 1.2944x; 1.2118x over previous
//
#include <hip/hip_runtime.h>
#include <stdint.h>

#define BI 128
#define BT 128
#define RR 36
#define WW 50
#define DD 1024
#define NN 6400       /* fg row stride, static */
#define SEPS 1e-6f

typedef __attribute__((ext_vector_type(8))) short short8v;
typedef __attribute__((ext_vector_type(4))) float float4v;

__device__ __forceinline__ unsigned short f2bf(float f){
  unsigned u = __float_as_uint(f);
  return (unsigned short)((u + 0x7FFFu + ((u >> 16) & 1u)) >> 16);
}

// ---- exclusive prefix scan of il (128) and cl (128); dst[128] = total ----
__global__ __launch_bounds__(256) void prefix_kernel(
    const int* __restrict__ il, const int* __restrict__ cl,
    int* __restrict__ rowoff, int* __restrict__ coloff){
  __shared__ int buf[2][128];
  const int t = threadIdx.x;
  const int which = t >> 7, j = t & 127;
  const int v = which ? cl[j] : il[j];
  buf[which][j] = v;
  __syncthreads();
  #pragma unroll
  for (int off = 1; off < 128; off <<= 1){
    int x = (j >= off) ? buf[which][j - off] : 0;
    __syncthreads();
    buf[which][j] += x;
    __syncthreads();
  }
  int* dst = which ? coloff : rowoff;
  dst[j] = buf[which][j] - v;                 // exclusive
  if (j == 127) dst[128] = buf[which][127];   // total (M' / N')
}

// ---- gather valid rows + f32->bf16 convert. Block = one source row. ----
__global__ __launch_bounds__(256) void gather_cvt_kernel(
    const float* __restrict__ imgs, const float* __restrict__ caps,
    const int* __restrict__ il, const int* __restrict__ cl,
    const int* __restrict__ rowoff, const int* __restrict__ coloff,
    unsigned short* __restrict__ Ab, unsigned short* __restrict__ Bb){
  const int b = blockIdx.x;
  const int t = threadIdx.x;
  if (b < BI * RR){
    const int i = b / RR, r = b % RR;
    if (r >= il[i]) return;
    const float4 v = *(const float4*)(imgs + (size_t)b * DD + t * 4);
    ushort4 o = make_ushort4(f2bf(v.x), f2bf(v.y), f2bf(v.z), f2bf(v.w));
    *(ushort4*)(Ab + (size_t)(rowoff[i] + r) * DD + t * 4) = o;
  } else {
    const int bb = b - BI * RR;
    const int c = bb / WW, w = bb % WW;
    if (w >= cl[c]) return;
    const float4 v = *(const float4*)(caps + (size_t)bb * DD + t * 4);
    ushort4 o = make_ushort4(f2bf(v.x), f2bf(v.y), f2bf(v.z), f2bf(v.w));
    *(ushort4*)(Bb + (size_t)(coloff[c] + w) * DD + t * 4) = o;
  }
}

// ---- m97-structure 128x128x64 GEMM over compacted rows; early-exit tiles ----
__global__ __launch_bounds__(256) void gemm_kernel(
    const unsigned short* __restrict__ A, const unsigned short* __restrict__ B,
    const int* __restrict__ rowoff, const int* __restrict__ coloff,
    float* __restrict__ C){
  __shared__ __align__(16) unsigned char LDS[32768];
  const int bx = blockIdx.x;
  const int swz = (bx & 7) * 225 + (bx >> 3);     // 1800 = 8*225, bijective
  const int mb = swz / 50, nb = swz % 50;
  const int m0 = mb * 128, n0 = nb * 128;
  const int Mp = rowoff[BI];                      // M' (runtime)
  const int Np = coloff[BT];                      // N'
  if (m0 >= Mp || n0 >= Np) return;               // uniform early-exit

  const int tid = threadIdx.x;
  const int lane = tid & 63, wv = tid >> 6;
  const int l15 = lane & 15, lhi = lane >> 4;
  const int wr = wv >> 1, wc = wv & 1;            // 2x2 wave grid, 64x64/wave

  const unsigned short* sA[4];
  const unsigned short* sB[4];
  #pragma unroll
  for (int j = 0; j < 4; j++){
    int u = j * 256 + tid;                        // 16B unit 0..1023
    int row = u >> 3;
    int kg = (u & 7) ^ (row & 7);                 // source pre-swizzle
    sA[j] = A + (size_t)(m0 + row) * DD + kg * 8;
    sB[j] = B + (size_t)(n0 + row) * DD + kg * 8;
  }

  float4v acc[4][4];
  #pragma unroll
  for (int a1 = 0; a1 < 4; a1++)
    #pragma unroll
    for (int b1 = 0; b1 < 4; b1++)
      acc[a1][b1] = (float4v){0.f, 0.f, 0.f, 0.f};

  for (int ch = 0; ch < 16; ch++){
    __syncthreads();
    #pragma unroll
    for (int j = 0; j < 4; j++){
      __builtin_amdgcn_global_load_lds(
          (const __attribute__((address_space(1))) void*)(sA[j] + ch * 64),
          (__attribute__((address_space(3))) void*)(LDS + (j * 256 + tid) * 16),
          16, 0, 0);
      __builtin_amdgcn_global_load_lds(
          (const __attribute__((address_space(1))) void*)(sB[j] + ch * 64),
          (__attribute__((address_space(3))) void*)(LDS + 16384 + (j * 256 + tid) * 16),
          16, 0, 0);
    }
    __syncthreads();
    #pragma unroll
    for (int s = 0; s < 2; s++){
      int kb = s * 4 + lhi;
      short8v af[4], bf[4];
      #pragma unroll
      for (int tr = 0; tr < 4; tr++){
        int row = wr * 64 + tr * 16 + l15;
        af[tr] = *(const short8v*)(LDS + (row * 8 + (kb ^ (row & 7))) * 16);
      }
      #pragma unroll
      for (int tw = 0; tw < 4; tw++){
        int row = wc * 64 + tw * 16 + l15;
        bf[tw] = *(const short8v*)(LDS + 16384 + (row * 8 + (kb ^ (row & 7))) * 16);
      }
      #pragma unroll
      for (int tr = 0; tr < 4; tr++)
        #pragma unroll
        for (int tw = 0; tw < 4; tw++)
          acc[tr][tw] = __builtin_amdgcn_mfma_f32_16x16x32_bf16(
              af[tr], bf[tw], acc[tr][tw], 0, 0, 0);
    }
  }

  // C/D layout: col = lane&15, row = lhi*4 + j (m89/m91, validated R1/R2)
  #pragma unroll
  for (int tr = 0; tr < 4; tr++)
    #pragma unroll
    for (int tw = 0; tw < 4; tw++)
      #pragma unroll
      for (int j = 0; j < 4; j++){
        int m = m0 + wr * 64 + tr * 16 + lhi * 4 + j;
        int n = n0 + wc * 64 + tw * 16 + l15;
        C[(size_t)m * NN + n] = acc[tr][tw][j];
      }
}

// ---- wave-wide sum: DPP row_ror within 16, shfl_xor across 16/32 ----
template<int CTRL>
__device__ __forceinline__ float dpp_add(float x){
  int y = __builtin_amdgcn_mov_dpp(__float_as_int(x), CTRL, 0xF, 0xF, true);
  return x + __int_as_float(y);
}
__device__ __forceinline__ float waveAllSum(float x){
  x = dpp_add<0x121>(x);
  x = dpp_add<0x122>(x);
  x = dpp_add<0x124>(x);
  x = dpp_add<0x128>(x);
  x += __shfl_xor(x, 16);
  x += __shfl_xor(x, 32);
  return x;
}

// ---- per-wave Sinkhorn over compacted fg; lane = word index w ----
__global__ __launch_bounds__(256) void sink_kernel(
    const float* __restrict__ fg, const int* __restrict__ il,
    const int* __restrict__ cl, const int* __restrict__ rowoff,
    const int* __restrict__ coloff, float* __restrict__ out){
  const int lane = threadIdx.x & 63;
  const int gw = blockIdx.x * 4 + (threadIdx.x >> 6);
  const int i = gw >> 7, c = gw & 127;
  const int ilen = il[i];
  const int clen = cl[c];
  const float* base = fg + (size_t)rowoff[i] * NN + coloff[c];
  const int w = lane;

  const float inv_il = __fdividef(1.0f, (float)ilen);
  const float inv_cl = __fdividef(1.0f, (float)clen);
  const bool vw = (w < clen);

  float f[RR], p[RR];
  #pragma unroll
  for (int r = 0; r < RR; r++)
    f[r] = (r < ilen && vw) ? base[(size_t)r * NN + w] : 0.0f;
  #pragma unroll
  for (int r = 0; r < RR; r++)
    p[r] = (r < ilen && vw) ? __expf(f[r] * 20.0f - 20.0f) : 0.0f;

  float s0 = 0.f;
  #pragma unroll
  for (int r = 0; r < RR; r++) s0 += p[r];
  s0 = waveAllSum(s0);
  float sc = __fdividef(1.0f, s0 + SEPS);
  #pragma unroll
  for (int r = 0; r < RR; r++) p[r] *= sc;

  for (int it = 0; it < 3; it++){
    #pragma unroll
    for (int r = 0; r < RR; r++){
      float t = waveAllSum(p[r]);                 // u = rowsum + EPS
      p[r] *= __fdividef(inv_il, t + SEPS);
    }
    float v = 0.f;                                // colsum (in-lane)
    #pragma unroll
    for (int r = 0; r < RR; r++) v += p[r];
    float cs = __fdividef(inv_cl, v + SEPS);
    #pragma unroll
    for (int r = 0; r < RR; r++) p[r] *= cs;
  }

  float sim = 0.f;
  #pragma unroll
  for (int r = 0; r < RR; r++) sim = fmaf(f[r], p[r], sim);
  sim = waveAllSum(sim);
  if (lane == 0) out[i * BT + c] = sim;
}

extern "C" void kernel_launch(void* const* d_in, const int* in_sizes, int n_in,
                              void* d_out, int out_size, void* d_ws, size_t ws_size,
                              hipStream_t stream){
  const float* imgs = (const float*)d_in[0];
  const float* caps = (const float*)d_in[1];
  const int* il = (const int*)d_in[2];
  const int* cl = (const int*)d_in[3];
  float* out = (float*)d_out;

  unsigned short* Ab = (unsigned short*)d_ws;               // [4608][1024] bf16
  unsigned short* Bb = Ab + (size_t)BI * RR * DD;           // [6400][1024] bf16
  float* fg = (float*)(Bb + (size_t)BT * WW * DD);          // [4608][6400] f32
  int* rowoff = (int*)(fg + (size_t)BI * RR * NN);          // [129]
  int* coloff = rowoff + 129;                               // [129]

  prefix_kernel<<<1, 256, 0, stream>>>(il, cl, rowoff, coloff);
  gather_cvt_kernel<<<BI * RR + BT * WW, 256, 0, stream>>>(
      imgs, caps, il, cl, rowoff, coloff, Ab, Bb);
  gemm_kernel<<<36 * 50, 256, 0, stream>>>(Ab, Bb, rowoff, coloff, fg);
  sink_kernel<<<(BI * BT) / 4, 256, 0, stream>>>(fg, il, cl, rowoff, coloff, out);
}